// Round 11
// baseline (276.074 us; speedup 1.0000x reference)
//
#include <hip/hip_runtime.h>
#include <hip/hip_bf16.h>

// SpikingSelfAttention: T=4 B=32 C=384 N=256 NH=8 D=48
#define T_  4
#define B_  32
#define C_  384
#define N_  256
#define NH_ 8
#define D_  48

typedef __attribute__((ext_vector_type(8))) short bf16x8;
typedef __attribute__((ext_vector_type(4))) float f32x4;

__device__ __forceinline__ float bf2f(unsigned short s) {
    return __uint_as_float(((unsigned int)s) << 16);
}
__device__ __forceinline__ unsigned short f2bf(float f) {
    __hip_bfloat16 h = __float2bfloat16(f);
    return __builtin_bit_cast(unsigned short, h);
}

// ---- K0: split fp32 weights into hi/lo bf16, FRAGMENT-MAJOR [otile24][ks12][lane64][8] ----
__global__ __launch_bounds__(256) void k_wsplit(const float* __restrict__ w0,
                                                const float* __restrict__ w1,
                                                const float* __restrict__ w2,
                                                const float* __restrict__ w3,
                                                unsigned short* __restrict__ hi,
                                                unsigned short* __restrict__ lo) {
    const float* w = (blockIdx.y==0) ? w0 : (blockIdx.y==1) ? w1 : (blockIdx.y==2) ? w2 : w3;
    int g = blockIdx.x*256 + threadIdx.x;            // 0..18431 (72 blocks)
    int otile = g / 768;
    int rem = g - otile*768;
    int lane = rem & 63;
    int o  = otile*16 + (lane & 15);
    int k0 = (rem >> 6)*32 + (lane >> 4)*8;
    const float* src = w + (size_t)o*C_ + k0;
    unsigned short h8[8], l8[8];
    #pragma unroll
    for (int j=0;j<8;++j) {
        float f = src[j];
        h8[j] = f2bf(f);
        l8[j] = f2bf(f - bf2f(h8[j]));
    }
    size_t dst = (size_t)blockIdx.y*147456 + (size_t)g*8;
    *(uint4*)(hi + dst) = *(uint4*)h8;
    *(uint4*)(lo + dst) = *(uint4*)l8;
}

// ---- K1: LIF over T on x; spike BITS fragment-major bytes [t][b][nt16][ks12][lane64] ----
__global__ __launch_bounds__(256) void k_lif1(const float* __restrict__ x,
                                              unsigned char* __restrict__ s0b) {
    __shared__ unsigned short Tt[64*72];
    const int tid = threadIdx.x;
    const int b  = blockIdx.x;
    const int c0 = blockIdx.y * 64;
    const int n0 = blockIdx.z * 64;
    const int ci = tid >> 2;
    const int nj = (tid & 3) * 16;
    float v[16];
    #pragma unroll
    for (int i=0;i<16;++i) v[i]=0.f;
    for (int t = 0; t < T_; ++t) {
        const float* xp = x + (((size_t)t*B_ + b)*C_ + c0 + ci)*N_ + n0 + nj;
        #pragma unroll
        for (int q=0;q<4;++q) {
            float4 f = *(const float4*)(xp + q*4);
            float e[4] = {f.x,f.y,f.z,f.w};
            #pragma unroll
            for (int j=0;j<4;++j) {
                int ii = q*4+j;
                float h = v[ii] + (e[j] - v[ii])*0.5f;
                bool sp = (h - 1.0f) >= 0.f;
                v[ii] = sp ? 0.f : h;
                Tt[(nj + ii)*72 + ci] = sp ? 0x3F80u : 0u;
            }
        }
        __syncthreads();
        #pragma unroll
        for (int half=0; half<2; ++half) {
            int e = tid + half*256;              // 0..511
            int nl = e >> 3, cbyte = e & 7;      // n-local, c-byte (8 c each)
            unsigned short tmp[8];
            *(uint4*)tmp = *(const uint4*)&Tt[nl*72 + cbyte*8];
            unsigned byte = 0;
            #pragma unroll
            for (int j=0;j<8;++j) byte |= (tmp[j] ? 1u : 0u) << j;
            int n = n0 + nl, c = c0 + cbyte*8;
            int ks = c >> 5, kc = (c >> 3) & 3;
            size_t dst = ((((size_t)(t*B_ + b)*16 + (n>>4))*12 + ks)*64) + kc*16 + (n & 15);
            s0b[dst] = (unsigned char)byte;
        }
        __syncthreads();
    }
}

// ---- K2: MFMA branch GEMM, 128x128 tiles, prefetch-pipelined; bits out [t][b][g32][o][4B] ----
struct Br2 {
    const unsigned short* whi[3];
    const unsigned short* wlo[3];
    const float *g[3], *be[3], *me[3], *va[3];
    unsigned char* outb[3];
};

__global__ __launch_bounds__(256, 2) void k_branch(const unsigned char* __restrict__ s0b, Br2 a) {
    __shared__ float Ep[32*132];
    __shared__ float BNi[128], BNo[128];
    __shared__ unsigned short LUT[2048];
    const int tid = threadIdx.x;
    const int z  = blockIdx.z;
    const int o0 = blockIdx.y * 128;
    const int bx = blockIdx.x;
    const int b  = bx >> 3;
    const int n0 = (bx & 7) * 32;
    const int g32 = n0 >> 5;
    const int w    = tid >> 6;
    const int lane = tid & 63;
    const int quad = lane >> 4;
    const int lc   = lane & 15;
    const unsigned short* __restrict__ Wgh = a.whi[z];
    const unsigned short* __restrict__ Wgl = a.wlo[z];

    #pragma unroll
    for (int j=0;j<8;++j) LUT[tid*8 + j] = ((tid >> j) & 1) ? 0x3F80u : 0u;
    if (tid < 128) {
        int o = o0 + tid;
        float inv = a.g[z][o] / sqrtf(a.va[z][o] + 1e-5f);
        BNi[tid] = inv;
        BNo[tid] = a.be[z][o] - a.me[z][o]*inv;
    }
    __syncthreads();

    const int base_ot = (o0 >> 4) + (w >> 1)*4;
    const unsigned short* pAh[4];
    const unsigned short* pAl[4];
    const unsigned char* pBY[4];
    #pragma unroll
    for (int mt=0;mt<4;++mt) {
        size_t off = (size_t)(base_ot + mt)*6144 + lane*8;
        pAh[mt] = Wgh + off;
        pAl[mt] = Wgl + off;
    }
    #pragma unroll
    for (int nt=0;nt<4;++nt) {
        int cb = (w&1)*64 + nt*16;           // col = t*32 + ns
        int t = cb >> 5;
        int ntile = (n0 >> 4) + ((cb >> 4) & 1);
        pBY[nt] = s0b + ((size_t)(t*B_ + b)*16 + ntile)*768 + lane;
    }

    f32x4 acc[4][4];
    #pragma unroll
    for (int mt=0;mt<4;++mt)
        #pragma unroll
        for (int nt=0;nt<4;++nt) { acc[mt][nt][0]=0.f; acc[mt][nt][1]=0.f; acc[mt][nt][2]=0.f; acc[mt][nt][3]=0.f; }

    // prologue loads
    unsigned char cby[4];
    bf16x8 cah[4], cal[4];
    #pragma unroll
    for (int nt=0;nt<4;++nt) { cby[nt] = *(pBY[nt]); pBY[nt] += 64; }
    #pragma unroll
    for (int mt=0;mt<4;++mt) {
        cah[mt] = *(const bf16x8*)(pAh[mt]); pAh[mt] += 512;
        cal[mt] = *(const bf16x8*)(pAl[mt]); pAl[mt] += 512;
    }

    #pragma unroll
    for (int ks = 0; ks < 12; ++ks) {
        unsigned char nby[4];
        bf16x8 nah[4], nal[4];
        if (ks < 11) {
            #pragma unroll
            for (int nt=0;nt<4;++nt) { nby[nt] = *(pBY[nt]); pBY[nt] += 64; }
            #pragma unroll
            for (int mt=0;mt<4;++mt) {
                nah[mt] = *(const bf16x8*)(pAh[mt]); pAh[mt] += 512;
                nal[mt] = *(const bf16x8*)(pAl[mt]); pAl[mt] += 512;
            }
        }
        bf16x8 bb[4];
        #pragma unroll
        for (int nt=0;nt<4;++nt) bb[nt] = *(const bf16x8*)&LUT[(int)cby[nt]*8];
        #pragma unroll
        for (int mt=0;mt<4;++mt)
            #pragma unroll
            for (int nt=0;nt<4;++nt) {
                acc[mt][nt] = __builtin_amdgcn_mfma_f32_16x16x32_bf16(cah[mt], bb[nt], acc[mt][nt], 0,0,0);
                acc[mt][nt] = __builtin_amdgcn_mfma_f32_16x16x32_bf16(cal[mt], bb[nt], acc[mt][nt], 0,0,0);
            }
        if (ks < 11) {
            #pragma unroll
            for (int nt=0;nt<4;++nt) cby[nt]=nby[nt];
            #pragma unroll
            for (int mt=0;mt<4;++mt) { cah[mt]=nah[mt]; cal[mt]=nal[mt]; }
        }
    }

    // epilogue: 4 rounds; Ep = 32 o x 128 col (col = t*32 + ns); 1-byte (8n) stores
    unsigned char* outb = a.outb[z];
    for (int r = 0; r < 4; ++r) {
        __syncthreads();
        int erow = (w>>1)*16 + quad*4;
        #pragma unroll
        for (int nt=0;nt<4;++nt) {
            int col = (w&1)*64 + nt*16 + lc;
            Ep[(erow+0)*132 + col] = acc[r][nt][0];
            Ep[(erow+1)*132 + col] = acc[r][nt][1];
            Ep[(erow+2)*132 + col] = acc[r][nt][2];
            Ep[(erow+3)*132 + col] = acc[r][nt][3];
        }
        __syncthreads();
        if (tid < 128) {
            int orow = tid >> 2;
            int bidx = tid & 3;
            int oloc = ((orow & 16) ? 64 : 0) + r*16 + (orow & 15);
            int o = o0 + oloc;
            float inv = BNi[oloc], off = BNo[oloc];
            float v[8];
            #pragma unroll
            for (int j=0;j<8;++j) v[j]=0.f;
            #pragma unroll
            for (int t=0;t<4;++t) {
                float4 f0 = *(const float4*)&Ep[orow*132 + t*32 + bidx*8];
                float4 f1 = *(const float4*)&Ep[orow*132 + t*32 + bidx*8 + 4];
                float e[8] = {f0.x,f0.y,f0.z,f0.w,f1.x,f1.y,f1.z,f1.w};
                unsigned byte = 0;
                #pragma unroll
                for (int j=0;j<8;++j) {
                    float y = e[j]*inv + off;
                    float h = v[j] + (y - v[j])*0.5f;
                    bool sp = (h - 1.0f) >= 0.f;
                    v[j] = sp ? 0.f : h;
                    byte |= (sp ? 1u : 0u) << j;
                }
                outb[(((size_t)(t*B_ + b)*8 + g32)*C_ + o)*4 + bidx] = (unsigned char)byte;
            }
        }
    }
}

// ---- K3: fused attention + attn-LIF per (b,h); bits in [t][b][g32][o][4B]; S2 frag-major bytes ----
__global__ __launch_bounds__(256) void k_attn(const unsigned char* __restrict__ qb,
                                              const unsigned char* __restrict__ kb,
                                              const unsigned char* __restrict__ vb,
                                              unsigned char* __restrict__ s2b) {
    __shared__ unsigned short Qt[256*72];        // [n][dd] bf16; pads 48..63 zero; reused for spikes
    __shared__ unsigned short KtVb[48*72];       // [dd2][dd1] bf16; pads 48..63 zero
    __shared__ unsigned long long KB[192], VB[192], QB[192];
    const int tid = threadIdx.x;
    const int w = tid >> 6, lane = tid & 63, quad = lane >> 4, lc = lane & 15;
    const int bh = blockIdx.x;
    const int b  = bh >> 3, hh = bh & 7;

    *(uint4*)&Qt[tid*72 + 48] = make_uint4(0,0,0,0);
    *(uint4*)&Qt[tid*72 + 56] = make_uint4(0,0,0,0);
    if (tid < 48) {
        *(uint4*)&KtVb[tid*72 + 48] = make_uint4(0,0,0,0);
        *(uint4*)&KtVb[tid*72 + 56] = make_uint4(0,0,0,0);
    }

    float vst[4][3][4];
    #pragma unroll
    for (int j=0;j<4;++j)
        #pragma unroll
        for (int nt=0;nt<3;++nt)
            #pragma unroll
            for (int r=0;r<4;++r) vst[j][nt][r]=0.f;

    for (int t = 0; t < T_; ++t) {
        __syncthreads();
        if (tid < 192) {
            int dd = tid >> 2, w64 = tid & 3;
            size_t s0 = (((size_t)(t*B_ + b)*8 + 2*w64)*C_ + hh*D_ + dd)*4;
            size_t s1 = s0 + (size_t)C_*4;
            KB[tid] = (unsigned long long)*(const unsigned int*)(kb + s0)
                    | ((unsigned long long)*(const unsigned int*)(kb + s1) << 32);
            VB[tid] = (unsigned long long)*(const unsigned int*)(vb + s0)
                    | ((unsigned long long)*(const unsigned int*)(vb + s1) << 32);
            QB[tid] = (unsigned long long)*(const unsigned int*)(qb + s0)
                    | ((unsigned long long)*(const unsigned int*)(qb + s1) << 32);
        }
        __syncthreads();
        {   // Qt expand: QB reads wave-broadcast; 6 vector writes per thread
            int q64 = tid >> 6, sh = tid & 63;
            #pragma unroll
            for (int c8=0; c8<6; ++c8) {
                unsigned short e8[8];
                #pragma unroll
                for (int j=0;j<8;++j)
                    e8[j] = ((QB[(c8*8+j)*4 + q64] >> sh) & 1ULL) ? 0x3F80u : 0u;
                *(uint4*)&Qt[tid*72 + c8*8] = *(uint4*)e8;
            }
        }
        #pragma unroll
        for (int i=0;i<9;++i) {
            int p = tid + i*256;
            if (p < 2304) {
                int dd1 = p / 48, dd2 = p - dd1*48;
                const unsigned long long* kr = &KB[dd1*4];
                const unsigned long long* vr = &VB[dd2*4];
                int c = __popcll(kr[0]&vr[0]) + __popcll(kr[1]&vr[1])
                      + __popcll(kr[2]&vr[2]) + __popcll(kr[3]&vr[3]);
                KtVb[dd2*72 + dd1] = f2bf((float)c);
            }
        }
        __syncthreads();
        f32x4 acc2[4][3];
        #pragma unroll
        for (int j=0;j<4;++j)
            #pragma unroll
            for (int nt=0;nt<3;++nt) { acc2[j][nt][0]=0.f; acc2[j][nt][1]=0.f; acc2[j][nt][2]=0.f; acc2[j][nt][3]=0.f; }
        #pragma unroll
        for (int k2=0; k2<2; ++k2) {
            bf16x8 bfr[3];
            #pragma unroll
            for (int nt=0;nt<3;++nt)
                bfr[nt] = *(const bf16x8*)&KtVb[(nt*16 + lc)*72 + k2*32 + quad*8];
            #pragma unroll
            for (int j=0;j<4;++j) {
                bf16x8 af = *(const bf16x8*)&Qt[((w*4 + j)*16 + lc)*72 + k2*32 + quad*8];
                #pragma unroll
                for (int nt=0;nt<3;++nt)
                    acc2[j][nt] = __builtin_amdgcn_mfma_f32_16x16x32_bf16(af, bfr[nt], acc2[j][nt], 0,0,0);
            }
        }
        #pragma unroll
        for (int j=0;j<4;++j) {
            int nr = (w*4 + j)*16 + quad*4;
            #pragma unroll
            for (int nt=0;nt<3;++nt)
                #pragma unroll
                for (int r=0;r<4;++r) {
                    float y = acc2[j][nt][r]*0.125f;
                    float vv = vst[j][nt][r];
                    float h = vv + (y - vv)*0.5f;
                    bool s = (h - 1.0f) >= 0.f;
                    vst[j][nt][r] = s ? 0.f : h;
                    Qt[(nr + r)*72 + nt*16 + lc] = s ? 0x3F80u : 0u;
                }
        }
        __syncthreads();
        {
            #pragma unroll
            for (int c8=0; c8<6; ++c8) {
                unsigned short tmp[8];
                *(uint4*)tmp = *(const uint4*)&Qt[tid*72 + c8*8];
                unsigned byte = 0;
                #pragma unroll
                for (int j=0;j<8;++j) byte |= (tmp[j] ? 1u : 0u) << j;
                int ci = hh*6 + c8;
                int ks = ci >> 2, kc = ci & 3;
                size_t dst = ((((size_t)(t*B_ + b)*16 + (tid>>4))*12 + ks)*64) + kc*16 + (tid & 15);
                s2b[dst] = (unsigned char)byte;
            }
        }
    }
}

// ---- K5: proj MFMA GEMM, 128x128 single-t tiles, prefetch-pipelined, direct stores ----
__global__ __launch_bounds__(256, 2) void k_proj(const unsigned char* __restrict__ s2b,
        const unsigned short* __restrict__ Wgh, const unsigned short* __restrict__ Wgl,
        const float* __restrict__ pb,
        const float* __restrict__ g, const float* __restrict__ be,
        const float* __restrict__ me, const float* __restrict__ va,
        float* __restrict__ out) {
    __shared__ float BNi[128], BNo[128];
    __shared__ unsigned short LUT[2048];
    const int tid = threadIdx.x;
    const int o0 = blockIdx.y * 128;
    const int bx = blockIdx.x;                   // 0..255: t(4) x b(32) x half(2)
    const int t  = bx >> 6;
    const int b  = (bx >> 1) & 31;
    const int n0 = (bx & 1) * 128;
    const int w    = tid >> 6;
    const int lane = tid & 63;
    const int quad = lane >> 4;
    const int lc   = lane & 15;

    #pragma unroll
    for (int j=0;j<8;++j) LUT[tid*8 + j] = ((tid >> j) & 1) ? 0x3F80u : 0u;
    if (tid < 128) {
        int o = o0 + tid;
        float inv = g[o] / sqrtf(va[o] + 1e-5f);
        BNi[tid] = inv;
        BNo[tid] = be[o] - me[o]*inv + pb[o]*inv;
    }
    __syncthreads();

    const int base_ot = (o0 >> 4) + (w >> 1)*4;
    const unsigned short* pAh[4];
    const unsigned short* pAl[4];
    const unsigned char* pBY[4];
    #pragma unroll
    for (int mt=0;mt<4;++mt) {
        size_t off = (size_t)(base_ot + mt)*6144 + lane*8;
        pAh[mt] = Wgh + off;
        pAl[mt] = Wgl + off;
    }
    #pragma unroll
    for (int nt=0;nt<4;++nt) {
        int cb = (w&1)*64 + nt*16;
        int ntile = (n0 >> 4) + (cb >> 4);
        pBY[nt] = s2b + ((size_t)(t*B_ + b)*16 + ntile)*768 + lane;
    }

    f32x4 acc[4][4];
    #pragma unroll
    for (int mt=0;mt<4;++mt)
        #pragma unroll
        for (int nt=0;nt<4;++nt) { acc[mt][nt][0]=0.f; acc[mt][nt][1]=0.f; acc[mt][nt][2]=0.f; acc[mt][nt][3]=0.f; }

    unsigned char cby[4];
    bf16x8 cah[4], cal[4];
    #pragma unroll
    for (int nt=0;nt<4;++nt) { cby[nt] = *(pBY[nt]); pBY[nt] += 64; }
    #pragma unroll
    for (int mt=0;mt<4;++mt) {
        cah[mt] = *(const bf16x8*)(pAh[mt]); pAh[mt] += 512;
        cal[mt] = *(const bf16x8*)(pAl[mt]); pAl[mt] += 512;
    }

    #pragma unroll
    for (int ks = 0; ks < 12; ++ks) {
        unsigned char nby[4];
        bf16x8 nah[4], nal[4];
        if (ks < 11) {
            #pragma unroll
            for (int nt=0;nt<4;++nt) { nby[nt] = *(pBY[nt]); pBY[nt] += 64; }
            #pragma unroll
            for (int mt=0;mt<4;++mt) {
                nah[mt] = *(const bf16x8*)(pAh[mt]); pAh[mt] += 512;
                nal[mt] = *(const bf16x8*)(pAl[mt]); pAl[mt] += 512;
            }
        }
        bf16x8 bb[4];
        #pragma unroll
        for (int nt=0;nt<4;++nt) bb[nt] = *(const bf16x8*)&LUT[(int)cby[nt]*8];
        #pragma unroll
        for (int mt=0;mt<4;++mt)
            #pragma unroll
            for (int nt=0;nt<4;++nt) {
                acc[mt][nt] = __builtin_amdgcn_mfma_f32_16x16x32_bf16(cah[mt], bb[nt], acc[mt][nt], 0,0,0);
                acc[mt][nt] = __builtin_amdgcn_mfma_f32_16x16x32_bf16(cal[mt], bb[nt], acc[mt][nt], 0,0,0);
            }
        if (ks < 11) {
            #pragma unroll
            for (int nt=0;nt<4;++nt) cby[nt]=nby[nt];
            #pragma unroll
            for (int mt=0;mt<4;++mt) { cah[mt]=nah[mt]; cal[mt]=nal[mt]; }
        }
    }

    // direct epilogue: BN + scalar stores (16-lane 64B segments per quad-row)
    float* obase = out + ((size_t)t*B_ + b)*C_*N_;
    #pragma unroll
    for (int mt=0;mt<4;++mt) {
        #pragma unroll
        for (int r=0;r<4;++r) {
            int oloc = (w>>1)*64 + mt*16 + quad*4 + r;
            int o = o0 + oloc;
            float inv = BNi[oloc], off = BNo[oloc];
            float* orow = obase + (size_t)o*N_ + n0 + (w&1)*64 + lc;
            #pragma unroll
            for (int nt=0;nt<4;++nt)
                orow[nt*16] = acc[mt][nt][r]*inv + off;
        }
    }
}

extern "C" void kernel_launch(void* const* d_in, const int* in_sizes, int n_in,
                              void* d_out, int out_size, void* d_ws, size_t ws_size,
                              hipStream_t stream) {
    const float* x  = (const float*)d_in[0];
    char* ws = (char*)d_ws;
    unsigned char* S0B = (unsigned char*)ws;
    unsigned char* QB = (unsigned char*)(ws + 2097152);
    unsigned char* KB = (unsigned char*)(ws + 4194304);
    unsigned char* VB = (unsigned char*)(ws + 6291456);
    unsigned char* S2B = (unsigned char*)(ws + 8388608);
    unsigned short* WHI = (unsigned short*)(ws + 100663296);
    unsigned short* WLO = WHI + 4*147456;

    k_wsplit<<<dim3(72,4), 256, 0, stream>>>(
        (const float*)d_in[2], (const float*)d_in[7], (const float*)d_in[12],
        (const float*)d_in[17], WHI, WLO);

    k_lif1<<<dim3(32,6,4), 256, 0, stream>>>(x, S0B);

    Br2 ba;
    for (int z=0;z<3;++z) { ba.whi[z] = WHI + z*147456; ba.wlo[z] = WLO + z*147456; }
    ba.g[0]=(const float*)d_in[3];  ba.be[0]=(const float*)d_in[4];
    ba.me[0]=(const float*)d_in[5]; ba.va[0]=(const float*)d_in[6];
    ba.g[1]=(const float*)d_in[8];  ba.be[1]=(const float*)d_in[9];
    ba.me[1]=(const float*)d_in[10]; ba.va[1]=(const float*)d_in[11];
    ba.g[2]=(const float*)d_in[13]; ba.be[2]=(const float*)d_in[14];
    ba.me[2]=(const float*)d_in[15]; ba.va[2]=(const float*)d_in[16];
    ba.outb[0]=QB; ba.outb[1]=KB; ba.outb[2]=VB;
    k_branch<<<dim3(256, 3, 3), 256, 0, stream>>>(S0B, ba);

    k_attn<<<B_*NH_, 256, 0, stream>>>(QB, KB, VB, S2B);

    k_proj<<<dim3(256, 3), 256, 0, stream>>>(S2B,
        WHI + 3*147456, WLO + 3*147456,
        (const float*)d_in[18],
        (const float*)d_in[19], (const float*)d_in[20],
        (const float*)d_in[21], (const float*)d_in[22],
        (float*)d_out);
}